// Round 11
// baseline (471.044 us; speedup 1.0000x reference)
//
#include <hip/hip_runtime.h>

// Ensemble of 8 LSTMs (H=64, input dim 1) over T=1024, B=128, then (B,T)@Wl^T+bl.
//
// v11: two-pair software pipeline (anti-phased independent chains per block).
//  - 256 blocks (8 L x 32 groups of 4 batches) x 256 threads (4 waves), 1/CU.
//    Pairs alpha={b0,b0+1}, beta={b0+2,b0+3} advance in anti-phase: the cell
//    update (VALU/trans) of one pair executes in the MFMA-pipe shadow of the
//    other pair's gate MFMAs (separate pipes, no data dependency).
//  - Per pair: v10 math. A rows = h[batch m&1] (dup8, bf16); B = Whh bf16
//    pre-scaled by 1/ln2 (tanh gate 2/ln2); bias via MFMA C-init; 8 MFMA/wave.
//    D: col=unit-in-tile, batch=reg&1 -> lane's cell (bb=kg&1, u=16w+col),
//    single cndmask select; all-lane dup2 cell compute (benign dup writes).
//  - h single-buffered per pair (barriers separate read/write phases):
//      [read hA][MFMA_a][cells_b -> write hB] bar [read hB][MFMA_b][cells_a] bar
//  - h63 rings (fp32) -> v8-style post-loop projection; reduce kernel sums L.

#define LENA 8
#define NB 128
#define NT 1024
#define NH 64

typedef __attribute__((ext_vector_type(4))) float f32x4;
typedef __attribute__((ext_vector_type(8))) short bf16x8;

__device__ __forceinline__ short f2bf(float f) {
    unsigned u = __float_as_uint(f);
    unsigned r = (u + 0x7FFFu + ((u >> 16) & 1u)) >> 16;
    return (short)r;
}

__global__ __launch_bounds__(256, 1) void lstm_v11_kernel(
    const float* __restrict__ x, const float* __restrict__ hn,
    const float* __restrict__ Wih, const float* __restrict__ Whh,
    const float* __restrict__ bih, const float* __restrict__ bhh,
    const float* __restrict__ Wl, float* __restrict__ ws)
{
    __shared__ float x4[NT][4];                      // 16 KB
    __shared__ float ring[NT][4];                    // 16 KB: h63 history (fp32)
    __shared__ __align__(16) short hA[16][8];        // 256 B: pair-alpha h (swizzled)
    __shared__ __align__(16) short hB[16][8];        // 256 B: pair-beta h

    const int tid = threadIdx.x;
    const int w   = tid >> 6;        // wave 0..3: unit-tile w
    const int l   = tid & 63;
    const int col = l & 15;          // unit-in-tile
    const int kg  = l >> 4;          // k-group
    const int bb  = kg & 1;          // lane's batch within pair (dup2)
    const int li  = blockIdx.x >> 5; // LSTM 0..7
    const int bg  = blockIdx.x & 31; // 4-batch group
    const int b0  = bg * 4;

    // ---- stage x ----
    for (int i = tid; i < 4 * NT; i += 256) {
        int bx = i >> 10, t = i & (NT - 1);
        x4[t][bx] = x[(size_t)(b0 + bx) * NT + t];
    }
    // ---- stage h0 into swizzled hA/hB ----
    {
        int bsel = tid >> 6, u = tid & 63;
        float v = hn[((size_t)li * NB + b0 + bsel) * NH + u];
        int bbs = bsel & 1;
        int slot = bbs * 8 + ((u >> 3) ^ (2 * bbs));
        short hv = f2bf(v);
        if (bsel < 2) hA[slot][u & 7] = hv; else hB[slot][u & 7] = hv;
    }

    const float RLN2 = 1.44269504f;
    // ---- B-frags: bf[gate][khalf], row = 64g+16w+col, k = kh*32 + kg*8 + e ----
    bf16x8 bf[4][2];
    #pragma unroll
    for (int g = 0; g < 4; ++g) {
        const float sc = (g == 2) ? 2.0f * RLN2 : RLN2;
        const float* rp = Whh + ((size_t)li * 256 + 64 * g + 16 * w + col) * 64 + kg * 8;
        #pragma unroll
        for (int kh = 0; kh < 2; ++kh) {
            const float* q = rp + kh * 32;
            bf16x8 f;
            #pragma unroll
            for (int e = 0; e < 8; ++e) f[e] = f2bf(sc * q[e]);
            bf[g][kh] = f;
        }
    }
    // ---- per-lane cell constants: cell (bb, u_c=16w+col) ----
    const int u_c = 16 * w + col;
    float wih4[4];
    f32x4 cinit[4];
    #pragma unroll
    for (int g = 0; g < 4; ++g) {
        const float sc = (g == 2) ? 2.0f * RLN2 : RLN2;
        int rowc = li * 256 + 64 * g + u_c;
        wih4[g] = sc * Wih[rowc];
        float bv = sc * (bih[rowc] + bhh[rowc]);
        cinit[g][0] = bv; cinit[g][1] = bv; cinit[g][2] = bv; cinit[g][3] = bv;
    }

    // ---- A-read slots (same swizzle both pairs) ----
    const int b_r = col & 1;
    const int s0 = b_r * 8 + (kg ^ (2 * b_r));
    const int s1 = b_r * 8 + ((4 + kg) ^ (2 * b_r));
    // ---- h-write slot ----
    const int wslot = bb * 8 + ((u_c >> 3) ^ (2 * bb));
    const int wpos  = u_c & 7;
    const bool isring = (u_c == 63);

    float cstA = 0.0f, cstB = 0.0f;
    f32x4 accA[4], accB[4];

    __syncthreads();

    // ---- prologue: acc_beta = gates_beta(0) ----
    {
        bf16x8 a0 = *(const bf16x8*)&hB[s0][0];
        bf16x8 a1 = *(const bf16x8*)&hB[s1][0];
        #pragma unroll
        for (int g = 0; g < 4; ++g) {
            f32x4 a = __builtin_amdgcn_mfma_f32_16x16x32_bf16(a0, bf[g][0], cinit[g], 0, 0, 0);
            accB[g] = __builtin_amdgcn_mfma_f32_16x16x32_bf16(a1, bf[g][1], a, 0, 0, 0);
        }
    }
    __syncthreads();

    #pragma unroll 1
    for (int t = 0; t < NT; ++t) {
        // ---- first half: MFMA_alpha(t) || cells_beta(t) ----
        {
            bf16x8 a0 = *(const bf16x8*)&hA[s0][0];
            bf16x8 a1 = *(const bf16x8*)&hA[s1][0];
            #pragma unroll
            for (int g = 0; g < 4; ++g) {
                f32x4 a = __builtin_amdgcn_mfma_f32_16x16x32_bf16(a0, bf[g][0], cinit[g], 0, 0, 0);
                accA[g] = __builtin_amdgcn_mfma_f32_16x16x32_bf16(a1, bf[g][1], a, 0, 0, 0);
            }
            // cells for beta (uses accB from previous half; independent of MFMAs above)
            const float xv = x4[t][2 + bb];
            float gi = fmaf(xv, wih4[0], bb ? accB[0][1] : accB[0][0]);
            float gf = fmaf(xv, wih4[1], bb ? accB[1][1] : accB[1][0]);
            float gg = fmaf(xv, wih4[2], bb ? accB[2][1] : accB[2][0]);
            float go = fmaf(xv, wih4[3], bb ? accB[3][1] : accB[3][0]);
            float iv = __builtin_amdgcn_rcpf(1.0f + __builtin_amdgcn_exp2f(-gi));
            float fv = __builtin_amdgcn_rcpf(1.0f + __builtin_amdgcn_exp2f(-gf));
            float gt = fmaf(-2.0f, __builtin_amdgcn_rcpf(1.0f + __builtin_amdgcn_exp2f(gg)), 1.0f);
            float ov = __builtin_amdgcn_rcpf(1.0f + __builtin_amdgcn_exp2f(-go));
            cstB = fmaf(fv, cstB, iv * gt);
            float ct = fmaf(-2.0f, __builtin_amdgcn_rcpf(1.0f + __builtin_amdgcn_exp2f(2.88539008f * cstB)), 1.0f);
            float hh = ov * ct;
            hB[wslot][wpos] = f2bf(hh);
            if (isring) ring[t][2 + bb] = hh;
        }
        __syncthreads();
        // ---- second half: MFMA_beta(t+1) || cells_alpha(t) ----
        {
            bf16x8 a0 = *(const bf16x8*)&hB[s0][0];
            bf16x8 a1 = *(const bf16x8*)&hB[s1][0];
            #pragma unroll
            for (int g = 0; g < 4; ++g) {
                f32x4 a = __builtin_amdgcn_mfma_f32_16x16x32_bf16(a0, bf[g][0], cinit[g], 0, 0, 0);
                accB[g] = __builtin_amdgcn_mfma_f32_16x16x32_bf16(a1, bf[g][1], a, 0, 0, 0);
            }
            const float xv = x4[t][bb];
            float gi = fmaf(xv, wih4[0], bb ? accA[0][1] : accA[0][0]);
            float gf = fmaf(xv, wih4[1], bb ? accA[1][1] : accA[1][0]);
            float gg = fmaf(xv, wih4[2], bb ? accA[2][1] : accA[2][0]);
            float go = fmaf(xv, wih4[3], bb ? accA[3][1] : accA[3][0]);
            float iv = __builtin_amdgcn_rcpf(1.0f + __builtin_amdgcn_exp2f(-gi));
            float fv = __builtin_amdgcn_rcpf(1.0f + __builtin_amdgcn_exp2f(-gf));
            float gt = fmaf(-2.0f, __builtin_amdgcn_rcpf(1.0f + __builtin_amdgcn_exp2f(gg)), 1.0f);
            float ov = __builtin_amdgcn_rcpf(1.0f + __builtin_amdgcn_exp2f(-go));
            cstA = fmaf(fv, cstA, iv * gt);
            float ct = fmaf(-2.0f, __builtin_amdgcn_rcpf(1.0f + __builtin_amdgcn_exp2f(2.88539008f * cstA)), 1.0f);
            float hh = ov * ct;
            hA[wslot][wpos] = f2bf(hh);
            if (isring) ring[t][bb] = hh;
        }
        __syncthreads();
    }

    // ---- projection: wave w -> batch w; out[a] = sum_t ring[t][w]*Wl[a][t] ----
    {
        const int b = w;
        const int a = l & 7, ch = l >> 3;
        const float* wlp = Wl + (size_t)a * NT + ch * 128;
        const float* rg  = &ring[ch * 128][0];
        float pacc = 0.0f;
        #pragma unroll 4
        for (int i = 0; i < 128; ++i)
            pacc = fmaf(rg[i * 4 + b], wlp[i], pacc);
        pacc += __shfl_xor(pacc, 8);
        pacc += __shfl_xor(pacc, 16);
        pacc += __shfl_xor(pacc, 32);
        if (l < 8) ws[(size_t)blockIdx.x * 32 + b * 8 + a] = pacc;
    }
}

__global__ __launch_bounds__(256) void reduce_kernel(
    const float* __restrict__ ws, const float* __restrict__ bl, float* __restrict__ out)
{
    int tid = blockIdx.x * 256 + threadIdx.x;    // 0..1023
    if (tid >= NB * LENA) return;
    int b = tid >> 3, a = tid & 7;
    int bg = b >> 2, bx = b & 3;
    float s = bl[a];
    #pragma unroll
    for (int li = 0; li < LENA; ++li)
        s += ws[((size_t)(li * 32 + bg)) * 32 + bx * 8 + a];
    out[tid] = s;
}

extern "C" void kernel_launch(void* const* d_in, const int* in_sizes, int n_in,
                              void* d_out, int out_size, void* d_ws, size_t ws_size,
                              hipStream_t stream) {
    const float* x   = (const float*)d_in[0];
    const float* hn  = (const float*)d_in[1];
    const float* Wih = (const float*)d_in[2];
    const float* Whh = (const float*)d_in[3];
    const float* bih = (const float*)d_in[4];
    const float* bhh = (const float*)d_in[5];
    const float* Wl  = (const float*)d_in[6];
    const float* bl  = (const float*)d_in[7];
    float* out = (float*)d_out;
    float* ws  = (float*)d_ws;   // 256*32*4 = 32 KB

    lstm_v11_kernel<<<dim3(256), dim3(256), 0, stream>>>(x, hn, Wih, Whh, bih, bhh, Wl, ws);
    reduce_kernel<<<dim3(4), dim3(256), 0, stream>>>(ws, bl, out);
}

// Round 12
// 267.159 us; speedup vs baseline: 1.7632x; 1.7632x over previous
//
#include <hip/hip_runtime.h>

// Ensemble of 8 LSTMs (H=64, input dim 1) over T=1024, B=128, then (B,T)@Wl^T+bl.
//
// v12 = v10 (2-batch blocks, 512 blocks, 2 blocks/CU, 2 waves/SIMD) + critical-
// path surgery:
//  - kh0/kh1 MFMAs issued IN PARALLEL (kh1 C-init = 0), summed after the batch
//    select: removes the 2-deep MFMA dependency (~30 cyc) from the step chain.
//  - tanh pre-scale folded into gt': gt' = fmaf(-4/ln2, rcp, 2/ln2) so the cell
//    state carries the 2/ln2 factor; deletes a dependent v_mul before exp2.
//  - s_setprio(1) around the MFMA cluster (two co-resident blocks are phase-
//    independent -> T5 prerequisite holds).
//  - everything else identical to v10: A rows = h[batch m&1] (bf16, dup8);
//    B = Whh bf16 pre-scaled 1/ln2 (g gate 2/ln2); bias via MFMA C-init;
//    1 cell/lane (dup2), 1 barrier/step; h63 ring -> post-loop projection.

#define LENA 8
#define NB 128
#define NT 1024
#define NH 64

typedef __attribute__((ext_vector_type(4))) float f32x4;
typedef __attribute__((ext_vector_type(8))) short bf16x8;

__device__ __forceinline__ short f2bf(float f) {
    unsigned u = __float_as_uint(f);
    unsigned r = (u + 0x7FFFu + ((u >> 16) & 1u)) >> 16;
    return (short)r;
}

__global__ __launch_bounds__(256, 2) void lstm_v12_kernel(
    const float* __restrict__ x, const float* __restrict__ hn,
    const float* __restrict__ Wih, const float* __restrict__ Whh,
    const float* __restrict__ bih, const float* __restrict__ bhh,
    const float* __restrict__ Wl, float* __restrict__ ws)
{
    __shared__ float x2[NT][2];                      // 8 KB
    __shared__ float ring[NT][2];                    // 8 KB: h63 history
    __shared__ __align__(16) short hbuf[2][16][8];   // 512 B: ping-pong h, swizzled slots
    __shared__ float pws[2][2][8];                   // projection partials

    const int tid = threadIdx.x;
    const int w   = tid >> 6;        // wave 0..3: owns unit-tile w
    const int l   = tid & 63;
    const int col = l & 15;          // unit-in-tile (A/B row, D col)
    const int kg  = l >> 4;          // k-group
    const int bb  = kg & 1;          // lane's batch (kg and kg+2 duplicate)
    const int li  = blockIdx.x >> 6; // LSTM 0..7
    const int bg  = blockIdx.x & 63; // batch pair
    const int b0  = bg * 2;

    // ---- stage x ----
    for (int i = tid; i < 2 * NT; i += 256) {
        int bx = i >> 10, t = i & (NT - 1);
        x2[t][bx] = x[(size_t)(b0 + bx) * NT + t];
    }
    // ---- stage h0 into swizzled hbuf[0]: slot(b,s) = b*8 + (s ^ 2b) ----
    if (tid < 128) {
        int b = tid >> 6, u = tid & 63;
        float v = hn[((size_t)li * NB + b0 + b) * NH + u];
        int slot = b * 8 + ((u >> 3) ^ (2 * b));
        hbuf[0][slot][u & 7] = f2bf(v);
    }

    const float RLN2 = 1.44269504f;   // 1/ln2
    // ---- B-frags: bf[gate][khalf], row = 64g+16w+col, k = kh*32 + kg*8 + e ----
    bf16x8 bf[4][2];
    #pragma unroll
    for (int g = 0; g < 4; ++g) {
        const float sc = (g == 2) ? 2.0f * RLN2 : RLN2;
        const float* rp = Whh + ((size_t)li * 256 + 64 * g + 16 * w + col) * 64 + kg * 8;
        #pragma unroll
        for (int kh = 0; kh < 2; ++kh) {
            const float* q = rp + kh * 32;
            bf16x8 f;
            #pragma unroll
            for (int e = 0; e < 8; ++e) f[e] = f2bf(sc * q[e]);
            bf[g][kh] = f;
        }
    }
    // ---- per-lane cell constants: cell (b=bb, u=16w+col) ----
    const int u_c = 16 * w + col;
    float wih4[4];
    f32x4 cinit[4];
    #pragma unroll
    for (int g = 0; g < 4; ++g) {
        const float sc = (g == 2) ? 2.0f * RLN2 : RLN2;
        int rowc = li * 256 + 64 * g + u_c;
        wih4[g] = sc * Wih[rowc];
        float bv = sc * (bih[rowc] + bhh[rowc]);
        cinit[g][0] = bv; cinit[g][1] = bv; cinit[g][2] = bv; cinit[g][3] = bv;
    }

    // ---- A-read slots: A row m = h[batch m&1]; lane reads batch b_r = col&1 ----
    const int b_r = col & 1;
    const int s0 = b_r * 8 + (kg ^ (2 * b_r));          // khalf0
    const int s1 = b_r * 8 + ((4 + kg) ^ (2 * b_r));    // khalf1
    // ---- h-write slot (batch-indexed: kg and kg+2 write same addr/value) ----
    const int wslot = bb * 8 + ((u_c >> 3) ^ (2 * bb));
    const int wpos  = u_c & 7;
    const bool isring = (u_c == 63);

    float cst = 0.0f;   // carries 2/ln2 scale internally

    __syncthreads();

    #pragma unroll 2
    for (int t = 0; t < NT; ++t) {
        const int p = t & 1;
        bf16x8 a0 = *(const bf16x8*)&hbuf[p][s0][0];
        bf16x8 a1 = *(const bf16x8*)&hbuf[p][s1][0];
        const float xv = x2[t][bb];

        const f32x4 zf = {0.0f, 0.0f, 0.0f, 0.0f};
        f32x4 m0[4], m1[4];
        __builtin_amdgcn_s_setprio(1);
        #pragma unroll
        for (int g = 0; g < 4; ++g) {
            m0[g] = __builtin_amdgcn_mfma_f32_16x16x32_bf16(a0, bf[g][0], cinit[g], 0, 0, 0);
            m1[g] = __builtin_amdgcn_mfma_f32_16x16x32_bf16(a1, bf[g][1], zf, 0, 0, 0);
        }
        __builtin_amdgcn_s_setprio(0);

        // select batch reg + combine k-halves + x term
        float gi = fmaf(xv, wih4[0], (bb ? m0[0][1] : m0[0][0]) + (bb ? m1[0][1] : m1[0][0]));
        float gf = fmaf(xv, wih4[1], (bb ? m0[1][1] : m0[1][0]) + (bb ? m1[1][1] : m1[1][0]));
        float gg = fmaf(xv, wih4[2], (bb ? m0[2][1] : m0[2][0]) + (bb ? m1[2][1] : m1[2][0]));
        float go = fmaf(xv, wih4[3], (bb ? m0[3][1] : m0[3][0]) + (bb ? m1[3][1] : m1[3][0]));

        float iv = __builtin_amdgcn_rcpf(1.0f + __builtin_amdgcn_exp2f(-gi));
        float fv = __builtin_amdgcn_rcpf(1.0f + __builtin_amdgcn_exp2f(-gf));
        // gt' = (2/ln2)*tanh(g) = fmaf(-4/ln2, rcp(1+e^{2g}), 2/ln2)
        float gt = fmaf(-5.77078016f, __builtin_amdgcn_rcpf(1.0f + __builtin_amdgcn_exp2f(gg)), 2.88539008f);
        float ov = __builtin_amdgcn_rcpf(1.0f + __builtin_amdgcn_exp2f(-go));
        cst = fmaf(fv, cst, iv * gt);   // cst = (2/ln2) * c_true
        // tanh(c_true) = 1 - 2/(1+exp2(cst))
        float ct = fmaf(-2.0f, __builtin_amdgcn_rcpf(1.0f + __builtin_amdgcn_exp2f(cst)), 1.0f);
        float hh = ov * ct;

        unsigned pk;
        asm("v_cvt_pk_bf16_f32 %0, %1, %2" : "=v"(pk) : "v"(hh), "v"(hh));
        hbuf[p ^ 1][wslot][wpos] = (short)(pk & 0xffffu);
        if (isring) ring[t][bb] = hh;
        __syncthreads();
    }

    // ---- projection: wave w -> batch b=w>>1, half p2=w&1 ----
    {
        const int b = w >> 1, p2 = w & 1;
        const int a = l & 7, ch = l >> 3;
        const int tb = p2 * 512 + ch * 64;
        const float* wlp = Wl + (size_t)a * NT + tb;
        float pacc = 0.0f;
        #pragma unroll 4
        for (int i = 0; i < 64; ++i)
            pacc = fmaf(ring[tb + i][b], wlp[i], pacc);
        pacc += __shfl_xor(pacc, 8);
        pacc += __shfl_xor(pacc, 16);
        pacc += __shfl_xor(pacc, 32);
        if (l < 8) pws[b][p2][a] = pacc;
    }
    __syncthreads();
    if (tid < 16) {
        int b = tid >> 3, a = tid & 7;
        ws[((size_t)blockIdx.x * 2 + b) * 8 + a] = pws[b][0][a] + pws[b][1][a];
    }
}

__global__ __launch_bounds__(256) void reduce_kernel(
    const float* __restrict__ ws, const float* __restrict__ bl, float* __restrict__ out)
{
    int tid = blockIdx.x * 256 + threadIdx.x;    // 0..1023
    if (tid >= NB * LENA) return;
    int b = tid >> 3, a = tid & 7;
    int bg = b >> 1, bx = b & 1;
    float s = bl[a];
    #pragma unroll
    for (int li = 0; li < LENA; ++li)
        s += ws[(((size_t)li * 64 + bg) * 2 + bx) * 8 + a];
    out[tid] = s;
}

extern "C" void kernel_launch(void* const* d_in, const int* in_sizes, int n_in,
                              void* d_out, int out_size, void* d_ws, size_t ws_size,
                              hipStream_t stream) {
    const float* x   = (const float*)d_in[0];
    const float* hn  = (const float*)d_in[1];
    const float* Wih = (const float*)d_in[2];
    const float* Whh = (const float*)d_in[3];
    const float* bih = (const float*)d_in[4];
    const float* bhh = (const float*)d_in[5];
    const float* Wl  = (const float*)d_in[6];
    const float* bl  = (const float*)d_in[7];
    float* out = (float*)d_out;
    float* ws  = (float*)d_ws;   // 512*2*8*4 = 32 KB

    lstm_v12_kernel<<<dim3(512), dim3(256), 0, stream>>>(x, hn, Wih, Whh, bih, bhh, Wl, ws);
    reduce_kernel<<<dim3(4), dim3(256), 0, stream>>>(ws, bl, out);
}

// Round 13
// 254.999 us; speedup vs baseline: 1.8472x; 1.0477x over previous
//
#include <hip/hip_runtime.h>

// Ensemble of 8 LSTMs (H=64, input dim 1) over T=1024, B=128, then (B,T)@Wl^T+bl.
//
// v13 = v10 geometry (512 blocks x 4 waves, 2 blocks/CU, 2 waves/SIMD) +
// schedule pinning:
//  - chained MFMA per gate (bias via C-init; no extra adds — v12's parallel-kh
//    was silently re-serialized by regalloc at VGPR=56).
//  - sched_barrier(0) after the MFMA cluster: forces all 8 MFMAs to issue as a
//    cluster with accumulators live (stops regalloc-driven serialization).
//  - s_setprio(1) around the MFMA cluster.
//  - xv prefetched before the cluster (lgkm hides under MFMA issue).
//  - folded tanh scale: cst carries 2/ln2; gt' = fmaf(-4/ln2, rcp, 2/ln2).
//  - A rows = h[batch m&1] (bf16, dup8); 1 cell/lane (dup2); swizzled hbuf;
//    1 barrier/step; h63 ring -> post-loop projection; reduce kernel sums L.

#define LENA 8
#define NB 128
#define NT 1024
#define NH 64

typedef __attribute__((ext_vector_type(4))) float f32x4;
typedef __attribute__((ext_vector_type(8))) short bf16x8;

__device__ __forceinline__ short f2bf(float f) {
    unsigned u = __float_as_uint(f);
    unsigned r = (u + 0x7FFFu + ((u >> 16) & 1u)) >> 16;
    return (short)r;
}

__global__ __launch_bounds__(256, 2) void lstm_v13_kernel(
    const float* __restrict__ x, const float* __restrict__ hn,
    const float* __restrict__ Wih, const float* __restrict__ Whh,
    const float* __restrict__ bih, const float* __restrict__ bhh,
    const float* __restrict__ Wl, float* __restrict__ ws)
{
    __shared__ float x2[NT][2];                      // 8 KB
    __shared__ float ring[NT][2];                    // 8 KB: h63 history
    __shared__ __align__(16) short hbuf[2][16][8];   // 512 B: ping-pong h, swizzled slots
    __shared__ float pws[2][2][8];                   // projection partials

    const int tid = threadIdx.x;
    const int w   = tid >> 6;        // wave 0..3: owns unit-tile w
    const int l   = tid & 63;
    const int col = l & 15;          // unit-in-tile (A/B row, D col)
    const int kg  = l >> 4;          // k-group
    const int bb  = kg & 1;          // lane's batch (kg and kg+2 duplicate)
    const int li  = blockIdx.x >> 6; // LSTM 0..7
    const int bg  = blockIdx.x & 63; // batch pair
    const int b0  = bg * 2;

    // ---- stage x ----
    for (int i = tid; i < 2 * NT; i += 256) {
        int bx = i >> 10, t = i & (NT - 1);
        x2[t][bx] = x[(size_t)(b0 + bx) * NT + t];
    }
    // ---- stage h0 into swizzled hbuf[0]: slot(b,s) = b*8 + (s ^ 2b) ----
    if (tid < 128) {
        int b = tid >> 6, u = tid & 63;
        float v = hn[((size_t)li * NB + b0 + b) * NH + u];
        int slot = b * 8 + ((u >> 3) ^ (2 * b));
        hbuf[0][slot][u & 7] = f2bf(v);
    }

    const float RLN2 = 1.44269504f;   // 1/ln2
    // ---- B-frags: bf[gate][khalf], row = 64g+16w+col, k = kh*32 + kg*8 + e ----
    bf16x8 bf[4][2];
    #pragma unroll
    for (int g = 0; g < 4; ++g) {
        const float sc = (g == 2) ? 2.0f * RLN2 : RLN2;
        const float* rp = Whh + ((size_t)li * 256 + 64 * g + 16 * w + col) * 64 + kg * 8;
        #pragma unroll
        for (int kh = 0; kh < 2; ++kh) {
            const float* q = rp + kh * 32;
            bf16x8 f;
            #pragma unroll
            for (int e = 0; e < 8; ++e) f[e] = f2bf(sc * q[e]);
            bf[g][kh] = f;
        }
    }
    // ---- per-lane cell constants: cell (b=bb, u=16w+col) ----
    const int u_c = 16 * w + col;
    float wih4[4];
    f32x4 cinit[4];
    #pragma unroll
    for (int g = 0; g < 4; ++g) {
        const float sc = (g == 2) ? 2.0f * RLN2 : RLN2;
        int rowc = li * 256 + 64 * g + u_c;
        wih4[g] = sc * Wih[rowc];
        float bv = sc * (bih[rowc] + bhh[rowc]);
        cinit[g][0] = bv; cinit[g][1] = bv; cinit[g][2] = bv; cinit[g][3] = bv;
    }

    // ---- A-read slots: A row m = h[batch m&1]; lane reads batch b_r = col&1 ----
    const int b_r = col & 1;
    const int s0 = b_r * 8 + (kg ^ (2 * b_r));          // khalf0
    const int s1 = b_r * 8 + ((4 + kg) ^ (2 * b_r));    // khalf1
    // ---- h-write slot (batch-indexed: kg and kg+2 write same addr/value) ----
    const int wslot = bb * 8 + ((u_c >> 3) ^ (2 * bb));
    const int wpos  = u_c & 7;
    const bool isring = (u_c == 63);

    float cst = 0.0f;   // carries 2/ln2 scale internally

    __syncthreads();

    #pragma unroll 2
    for (int t = 0; t < NT; ++t) {
        const int p = t & 1;
        bf16x8 a0 = *(const bf16x8*)&hbuf[p][s0][0];
        bf16x8 a1 = *(const bf16x8*)&hbuf[p][s1][0];
        const float xv = x2[t][bb];    // prefetched; lgkm hides under MFMA issue

        f32x4 acc[4];
        __builtin_amdgcn_s_setprio(1);
        #pragma unroll
        for (int g = 0; g < 4; ++g) {
            f32x4 a = __builtin_amdgcn_mfma_f32_16x16x32_bf16(a0, bf[g][0], cinit[g], 0, 0, 0);
            acc[g] = __builtin_amdgcn_mfma_f32_16x16x32_bf16(a1, bf[g][1], a, 0, 0, 0);
        }
        __builtin_amdgcn_s_setprio(0);
        __builtin_amdgcn_sched_barrier(0);   // keep MFMA cluster intact; accs live

        // select batch reg + x term
        float gi = fmaf(xv, wih4[0], bb ? acc[0][1] : acc[0][0]);
        float gf = fmaf(xv, wih4[1], bb ? acc[1][1] : acc[1][0]);
        float gg = fmaf(xv, wih4[2], bb ? acc[2][1] : acc[2][0]);
        float go = fmaf(xv, wih4[3], bb ? acc[3][1] : acc[3][0]);

        float iv = __builtin_amdgcn_rcpf(1.0f + __builtin_amdgcn_exp2f(-gi));
        float fv = __builtin_amdgcn_rcpf(1.0f + __builtin_amdgcn_exp2f(-gf));
        // gt' = (2/ln2)*tanh(g) = fmaf(-4/ln2, rcp(1+e^{2g}), 2/ln2)
        float gt = fmaf(-5.77078016f, __builtin_amdgcn_rcpf(1.0f + __builtin_amdgcn_exp2f(gg)), 2.88539008f);
        float ov = __builtin_amdgcn_rcpf(1.0f + __builtin_amdgcn_exp2f(-go));
        cst = fmaf(fv, cst, iv * gt);   // cst = (2/ln2) * c_true
        float ct = fmaf(-2.0f, __builtin_amdgcn_rcpf(1.0f + __builtin_amdgcn_exp2f(cst)), 1.0f);
        float hh = ov * ct;

        unsigned pk;
        asm("v_cvt_pk_bf16_f32 %0, %1, %2" : "=v"(pk) : "v"(hh), "v"(hh));
        hbuf[p ^ 1][wslot][wpos] = (short)(pk & 0xffffu);
        if (isring) ring[t][bb] = hh;
        __syncthreads();
    }

    // ---- projection: wave w -> batch b=w>>1, half p2=w&1 ----
    {
        const int b = w >> 1, p2 = w & 1;
        const int a = l & 7, ch = l >> 3;
        const int tb = p2 * 512 + ch * 64;
        const float* wlp = Wl + (size_t)a * NT + tb;
        float pacc = 0.0f;
        #pragma unroll 4
        for (int i = 0; i < 64; ++i)
            pacc = fmaf(ring[tb + i][b], wlp[i], pacc);
        pacc += __shfl_xor(pacc, 8);
        pacc += __shfl_xor(pacc, 16);
        pacc += __shfl_xor(pacc, 32);
        if (l < 8) pws[b][p2][a] = pacc;
    }
    __syncthreads();
    if (tid < 16) {
        int b = tid >> 3, a = tid & 7;
        ws[((size_t)blockIdx.x * 2 + b) * 8 + a] = pws[b][0][a] + pws[b][1][a];
    }
}

__global__ __launch_bounds__(256) void reduce_kernel(
    const float* __restrict__ ws, const float* __restrict__ bl, float* __restrict__ out)
{
    int tid = blockIdx.x * 256 + threadIdx.x;    // 0..1023
    if (tid >= NB * LENA) return;
    int b = tid >> 3, a = tid & 7;
    int bg = b >> 1, bx = b & 1;
    float s = bl[a];
    #pragma unroll
    for (int li = 0; li < LENA; ++li)
        s += ws[(((size_t)li * 64 + bg) * 2 + bx) * 8 + a];
    out[tid] = s;
}

extern "C" void kernel_launch(void* const* d_in, const int* in_sizes, int n_in,
                              void* d_out, int out_size, void* d_ws, size_t ws_size,
                              hipStream_t stream) {
    const float* x   = (const float*)d_in[0];
    const float* hn  = (const float*)d_in[1];
    const float* Wih = (const float*)d_in[2];
    const float* Whh = (const float*)d_in[3];
    const float* bih = (const float*)d_in[4];
    const float* bhh = (const float*)d_in[5];
    const float* Wl  = (const float*)d_in[6];
    const float* bl  = (const float*)d_in[7];
    float* out = (float*)d_out;
    float* ws  = (float*)d_ws;   // 512*2*8*4 = 32 KB

    lstm_v13_kernel<<<dim3(512), dim3(256), 0, stream>>>(x, hn, Wih, Whh, bih, bhh, Wl, ws);
    reduce_kernel<<<dim3(4), dim3(256), 0, stream>>>(ws, bl, out);
}